// Round 20
// baseline (281.386 us; speedup 1.0000x reference)
//
#include <hip/hip_runtime.h>
#include <hip/hip_bf16.h>
#include <math.h>

typedef __attribute__((ext_vector_type(8))) __bf16 bf16x8;
typedef __attribute__((ext_vector_type(4))) float f32x4;
typedef __hip_bfloat16 bf16;

#define D_MODEL 1024
#define F_FFN   4096
#define NHEAD   16
#define HDIM    64
#define SEQ     1024
#define BATCH   4

static __device__ __forceinline__ unsigned short bf_bits(bf16 h) {
  return __builtin_bit_cast(unsigned short, h);
}
static __device__ __forceinline__ float bf2f(unsigned short u) {
  unsigned v = (unsigned)u << 16;
  return __builtin_bit_cast(float, v);
}

template <int N>
static __device__ __forceinline__ void vwait() {
  asm volatile("s_waitcnt vmcnt(%0)" :: "n"(N) : "memory");
}

static __device__ __forceinline__ void gload_lds16(const bf16* src, bf16* dst) {
  __builtin_amdgcn_global_load_lds(
      (const __attribute__((address_space(1))) void*)src,
      (__attribute__((address_space(3))) void*)dst, 16, 0, 0);
}

// fast GELU: tanh form, |err| vs erf <= ~3e-4 absolute
static __device__ __forceinline__ float gelu_fast(float x) {
  float u = x * (0.7978845608f + 0.0356774081f * x * x);
  u = fminf(u, 15.f);
  float e = __expf(2.f * u);
  return 0.5f * x * (1.f + (e - 1.f) / (e + 1.f));
}

// ---------------- fused prep: 6 weight transposes + maskbits ----------------
__global__ __launch_bounds__(1024) void prep_kernel(
    const float* __restrict__ Wq, const float* __restrict__ Wk,
    const float* __restrict__ Wv, const float* __restrict__ Wo,
    const float* __restrict__ W1, const float* __restrict__ W2,
    const float* __restrict__ mask,
    bf16* __restrict__ Wqkv_t, bf16* __restrict__ Wo_t,
    bf16* __restrict__ W1_t, bf16* __restrict__ W2_t,
    unsigned* __restrict__ mbits) {
  __shared__ float tile[32][33];
  int bid = blockIdx.x;
  int tid = threadIdx.x;
  if (bid < 12288) {
    const float* W; bf16* Wt; int K, N, tx32, ty32;
    if (bid < 4096) {
      int w = bid >> 10;
      W  = (w == 0) ? Wq : (w == 1) ? Wk : (w == 2) ? Wv : Wo;
      Wt = (w < 3) ? Wqkv_t + (size_t)w * 1024 * 1024 : Wo_t;
      K = 1024; N = 1024;
      int t = bid & 1023; tx32 = t & 31; ty32 = t >> 5;
    } else if (bid < 8192) {
      W = W1; Wt = W1_t; K = 1024; N = 4096;
      int t = bid - 4096; tx32 = t & 127; ty32 = t >> 7;
    } else {
      W = W2; Wt = W2_t; K = 4096; N = 1024;
      int t = bid - 8192; tx32 = t & 31; ty32 = t >> 5;
    }
    int nb = tx32 * 32, kb = ty32 * 32;
    int tx = tid & 31, ty = tid >> 5;
    tile[ty][tx] = W[(size_t)(kb + ty) * N + nb + tx];
    __syncthreads();
    Wt[(size_t)(nb + ty) * K + kb + tx] = __float2bfloat16(tile[tx][ty]);
  } else {
    int gw = ((bid - 12288) * 1024 + tid) >> 6;
    int lane = tid & 63;
    const float4 m = reinterpret_cast<const float4*>(mask)[(size_t)gw * 64 + lane];
    unsigned long long b0 = __ballot(m.x > 0.f);
    unsigned long long b1 = __ballot(m.y > 0.f);
    unsigned long long b2 = __ballot(m.z > 0.f);
    unsigned long long b3 = __ballot(m.w > 0.f);
    if (lane < 8) {
      unsigned v = 0;
#pragma unroll
      for (int i = 0; i < 8; ++i) {
        int srcl = lane * 8 + i;
        v |= (((unsigned)(b0 >> srcl) & 1u) << (i * 4 + 0));
        v |= (((unsigned)(b1 >> srcl) & 1u) << (i * 4 + 1));
        v |= (((unsigned)(b2 >> srcl) & 1u) << (i * 4 + 2));
        v |= (((unsigned)(b3 >> srcl) & 1u) << (i * 4 + 3));
      }
      mbits[(size_t)gw * 8 + lane] = v;
    }
  }
}

// ---------------- LayerNorm: fp32 in -> bf16 out ----------------
__global__ __launch_bounds__(256) void layernorm_kernel(
    const float* __restrict__ x, const float* __restrict__ g,
    const float* __restrict__ bt, bf16* __restrict__ y) {
  int row = blockIdx.x;
  int tid = threadIdx.x;
  const float* xr = x + (size_t)row * D_MODEL;
  float4 v = reinterpret_cast<const float4*>(xr)[tid];
  float s  = v.x + v.y + v.z + v.w;
  float s2 = v.x * v.x + v.y * v.y + v.z * v.z + v.w * v.w;
  for (int o = 32; o; o >>= 1) { s += __shfl_xor(s, o); s2 += __shfl_xor(s2, o); }
  __shared__ float r1[4], r2[4];
  int wid = tid >> 6, lane = tid & 63;
  if (lane == 0) { r1[wid] = s; r2[wid] = s2; }
  __syncthreads();
  float tot  = r1[0] + r1[1] + r1[2] + r1[3];
  float tot2 = r2[0] + r2[1] + r2[2] + r2[3];
  float mean = tot * (1.f / D_MODEL);
  float var  = tot2 * (1.f / D_MODEL) - mean * mean;
  float rstd = rsqrtf(var + 1e-5f);
  float4 gg = reinterpret_cast<const float4*>(g)[tid];
  float4 bb = reinterpret_cast<const float4*>(bt)[tid];
  ushort4 o;
  o.x = bf_bits(__float2bfloat16((v.x - mean) * rstd * gg.x + bb.x));
  o.y = bf_bits(__float2bfloat16((v.y - mean) * rstd * gg.y + bb.y));
  o.z = bf_bits(__float2bfloat16((v.z - mean) * rstd * gg.z + bb.z));
  o.w = bf_bits(__float2bfloat16((v.w - mean) * rstd * gg.w + bb.w));
  reinterpret_cast<ushort4*>(y + (size_t)row * D_MODEL)[tid] = o;
}

enum { MODE_QKV = 0, MODE_O = 1, MODE_GELU = 2 };

#define MFMA16(a, b, c) __builtin_amdgcn_mfma_f32_16x16x32_bf16((a), (b), (c), 0, 0, 0)

// ======== 8-wave 256x256 BK=64 4-phase GEMM, dead-region staging ========
// 8 waves (2M x 4N), per-wave 128x64. LDS: 2 dbuf x (A[256][64]+B[256][64])
// = 128KB. Per K-tile: 4 quadrant phases {barrier; ds_read; stage dead-region
// chunks of tile T+2 (same dbuf); setprio 16 MFMA setprio}. Region death:
// A-quad0 after p1, all B after p2 (B-n0 reg-cached to p3), A-quad1 after p3.
// Stage plan: p2 -> A'{0-63,128-191}; p3 -> B'{0-63,128-191};
// p4 -> B'{64-127,192-255} + A'{64-127,192-255}. 8 loads/thread/tile uniform.
// Single counted vwait<8> per tile (last tile vwait<0>): retires exactly
// tile T's loads (5+ phase lead), T+1's stay in flight. Swizzle: 128B rows,
// phys seg = seg^(row&7), source pre-swizzled sg=(tid&7)^((tid>>3)&7);
// read seg (kk*4+lg)^(row&7).
template <int MODE>
__global__ __launch_bounds__(512, 1) void gemm8p_kernel(
    const bf16* __restrict__ A, const bf16* __restrict__ Bt,
    int M, int N, int K,
    const float* __restrict__ bias0, const float* __restrict__ bias1,
    const float* __restrict__ bias2,
    bf16* __restrict__ out_q, bf16* __restrict__ out_k, bf16* __restrict__ out_vt,
    bf16* __restrict__ out_bf) {
  __shared__ bf16 AS[2][256 * 64];
  __shared__ bf16 BS[2][256 * 64];
  int tid = threadIdx.x;
  int wid = tid >> 6, lane = tid & 63;
  int wm = wid >> 2, wn = wid & 3;
  int lrow = lane & 15, lg = lane >> 4;
  // bijective XCD swizzle (nwg % 8 == 0)
  int nwg = gridDim.x * gridDim.y;
  int lin = blockIdx.y * gridDim.x + blockIdx.x;
  int swz = (lin & 7) * (nwg >> 3) + (lin >> 3);
  int bxi = swz % gridDim.x, byi = swz / gridDim.x;
  int bm = byi * 256, bn = bxi * 256;
  int srow = tid >> 3;                     // 0..63
  int sg = (tid & 7) ^ ((tid >> 3) & 7);   // pre-swizzled source segment
  const bf16* Asrc = A  + (size_t)bm * K + sg * 8;
  const bf16* Bsrc = Bt + (size_t)bn * K + sg * 8;
  f32x4 acc[8][4] = {};
  const int NT = K / 64;
  int base_a = wm * 128;
  int base_b = (wn >> 1) * 128 + (wn & 1) * 64;

  auto stageA = [&](int t, int rowbase) {
    gload_lds16(Asrc + (size_t)(rowbase + srow) * K + t * 64,
                &AS[t & 1][rowbase * 64] + tid * 8);
  };
  auto stageB = [&](int t, int rowbase) {
    gload_lds16(Bsrc + (size_t)(rowbase + srow) * K + t * 64,
                &BS[t & 1][rowbase * 64] + tid * 8);
  };

  // prologue: stage tiles 0 and 1 fully (8 loads each)
#pragma unroll
  for (int rb = 0; rb < 256; rb += 64) stageA(0, rb);
#pragma unroll
  for (int rb = 0; rb < 256; rb += 64) stageB(0, rb);
#pragma unroll
  for (int rb = 0; rb < 256; rb += 64) stageA(1, rb);
#pragma unroll
  for (int rb = 0; rb < 256; rb += 64) stageB(1, rb);

  for (int t = 0; t < NT; ++t) {
    const char* as = (const char*)AS[t & 1];
    const char* bs = (const char*)BS[t & 1];
    bool more = (t + 2 < NT);
    bf16x8 af[4][2], bq0[2][2], bq1[2][2];
    // ---- phase 1: quad (m0,n0) ----
    if (t < NT - 1) vwait<8>(); else vwait<0>();
    __builtin_amdgcn_s_barrier();
#pragma unroll
    for (int f = 0; f < 4; ++f) {
      int ra = base_a + f * 16 + lrow;
#pragma unroll
      for (int kk = 0; kk < 2; ++kk)
        af[f][kk] = *reinterpret_cast<const bf16x8*>(
            as + ra * 128 + (((kk * 4 + lg) ^ (ra & 7)) << 4));
    }
#pragma unroll
    for (int g = 0; g < 2; ++g) {
      int rb = base_b + g * 16 + lrow;
#pragma unroll
      for (int kk = 0; kk < 2; ++kk)
        bq0[g][kk] = *reinterpret_cast<const bf16x8*>(
            bs + rb * 128 + (((kk * 4 + lg) ^ (rb & 7)) << 4));
    }
    __builtin_amdgcn_s_setprio(1);
#pragma unroll
    for (int f = 0; f < 4; ++f)
#pragma unroll
      for (int g = 0; g < 2; ++g)
#pragma unroll
        for (int kk = 0; kk < 2; ++kk)
          acc[f][g] = MFMA16(af[f][kk], bq0[g][kk], acc[f][g]);
    __builtin_amdgcn_s_setprio(0);
    // ---- phase 2: quad (m0,n1) ----
    __builtin_amdgcn_s_barrier();
#pragma unroll
    for (int g = 0; g < 2; ++g) {
      int rb = base_b + (2 + g) * 16 + lrow;
#pragma unroll
      for (int kk = 0; kk < 2; ++kk)
        bq1[g][kk] = *reinterpret_cast<const bf16x8*>(
            bs + rb * 128 + (((kk * 4 + lg) ^ (rb & 7)) << 4));
    }
    if (more) { stageA(t + 2, 0); stageA(t + 2, 128); }
    __builtin_amdgcn_s_setprio(1);
#pragma unroll
    for (int f = 0; f < 4; ++f)
#pragma unroll
      for (int g = 0; g < 2; ++g)
#pragma unroll
        for (int kk = 0; kk < 2; ++kk)
          acc[f][2 + g] = MFMA16(af[f][kk], bq1[g][kk], acc[f][2 + g]);
    __builtin_amdgcn_s_setprio(0);
    // ---- phase 3: quad (m1,n0) ----
    __builtin_amdgcn_s_barrier();
#pragma unroll
    for (int f = 0; f < 4; ++f) {
      int ra = base_a + 64 + f * 16 + lrow;
#pragma unroll
      for (int kk = 0; kk < 2; ++kk)
        af[f][kk] = *reinterpret_cast<const bf16x8*>(
            as + ra * 128 + (((kk * 4 + lg) ^ (ra & 7)) << 4));
    }
    if (more) { stageB(t + 2, 0); stageB(t + 2, 128); }
    __builtin_amdgcn_s_setprio(1);
#pragma unroll
    for (int f = 0; f < 4; ++f)
#pragma unroll
      for (int g = 0; g < 2; ++g)
#pragma unroll
        for (int kk = 0; kk < 2; ++kk)
          acc[4 + f][g] = MFMA16(af[f][kk], bq0[g][kk], acc[4 + f][g]);
    __builtin_amdgcn_s_setprio(0);
    // ---- phase 4: quad (m1,n1) ----
    __builtin_amdgcn_s_barrier();
    if (more) { stageB(t + 2, 64); stageB(t + 2, 192); stageA(t + 2, 64); stageA(t + 2, 192); }
    __builtin_amdgcn_s_setprio(1);
#pragma unroll
    for (int f = 0; f < 4; ++f)
#pragma unroll
      for (int g = 0; g < 2; ++g)
#pragma unroll
        for (int kk = 0; kk < 2; ++kk)
          acc[4 + f][2 + g] = MFMA16(af[f][kk], bq1[g][kk], acc[4 + f][2 + g]);
    __builtin_amdgcn_s_setprio(0);
  }

  // epilogue: C/D layout col=lane&15, row=(lane>>4)*4+reg  [m89-verified]
#pragma unroll
  for (int fm = 0; fm < 8; ++fm) {
#pragma unroll
    for (int fn = 0; fn < 4; ++fn) {
#pragma unroll
      for (int r = 0; r < 4; ++r) {
        int row = bm + base_a + fm * 16 + lg * 4 + r;
        int col = bn + base_b + fn * 16 + lrow;
        float v = acc[fm][fn][r];
        if (MODE == MODE_QKV) {
          if (col < 1024) {
            out_q[(size_t)row * 1024 + col] = __float2bfloat16((v + bias0[col]) * 0.125f);
          } else if (col < 2048) {
            out_k[(size_t)row * 1024 + (col - 1024)] = __float2bfloat16(v + bias1[col - 1024]);
          } else {
            int d = col - 2048;
            int b = row >> 10;
            int s = row & 1023;
            out_vt[((size_t)(b << 10) + d) * 1024 + s] = __float2bfloat16(v + bias2[d]);
          }
        } else {  // MODE_GELU
          float tv = v + bias0[col];
          out_bf[(size_t)row * N + col] = __float2bfloat16(gelu_fast(tv));
        }
      }
    }
  }
}

// ======== OUT split-K=2: 8-wave 256x64, BK=32, R=4 ring, lead-2 ========
__global__ __launch_bounds__(512, 2) void gemm_out_split_kernel(
    const bf16* __restrict__ A, const bf16* __restrict__ Bt, int K,
    bf16* __restrict__ psum0, bf16* __restrict__ psum1) {
  constexpr int R = 4;
  __shared__ bf16 AS[R][256 * 32];
  __shared__ bf16 BS[R][64 * 32];
  int tid = threadIdx.x;
  int wid = tid >> 6, lane = tid & 63;
  int wm4 = wid >> 1, wn2 = wid & 1;
  int lrow = lane & 15, lg = lane >> 4;
  int nwg = gridDim.x * gridDim.y;       // 512
  int lin = blockIdx.y * gridDim.x + blockIdx.x;
  int swz = (lin & 7) * (nwg >> 3) + (lin >> 3);
  int bxi = swz & 15;
  int rest = swz >> 4;
  int byi = rest & 15, z = rest >> 4;
  int bm = byi * 256, bn = bxi * 64;
  int kbeg = z * 2048;
  bf16* psum = z ? psum1 : psum0;
  int srow = tid >> 2;
  int sg = (tid & 3) ^ ((tid >> 3) & 3);
  const bf16* Asrc = A  + (size_t)bm * K + kbeg + sg * 8;
  const bf16* Bsrc = Bt + (size_t)bn * K + kbeg + sg * 8;
  f32x4 acc[4][2] = {};
  const int NT = 2048 / 32;

  auto stage = [&](int t) {
    int slot = t & 3;
    int k0 = t * 32;
#pragma unroll
    for (int j = 0; j < 2; ++j) {
      int row = j * 128 + srow;
      gload_lds16(Asrc + (size_t)row * K + k0, &AS[slot][(j * 512 + tid) * 8]);
    }
    if (wid < 4)
      gload_lds16(Bsrc + (size_t)srow * K + k0, &BS[slot][tid * 8]);
  };

  int sw = (lg ^ ((lrow >> 1) & 3)) << 4;
  stage(0); stage(1); stage(2);
  for (int t = 0; t < NT; ++t) {
    if (t < NT - 2) {
      if (wid < 4) vwait<6>(); else vwait<4>();
    } else if (t == NT - 2) {
      if (wid < 4) vwait<3>(); else vwait<2>();
    } else {
      vwait<0>();
    }
    __builtin_amdgcn_s_barrier();
    int slot = t & 3;
    const char* as = (const char*)AS[slot];
    const char* bs = (const char*)BS[slot];
    bf16x8 af[4], bfr[2];
#pragma unroll
    for (int f = 0; f < 4; ++f)
      af[f] = *reinterpret_cast<const bf16x8*>(as + (wm4 * 64 + f * 16 + lrow) * 64 + sw);
#pragma unroll
    for (int g = 0; g < 2; ++g)
      bfr[g] = *reinterpret_cast<const bf16x8*>(bs + (wn2 * 32 + g * 16 + lrow) * 64 + sw);
    if (t + 3 < NT) stage(t + 3);
    __builtin_amdgcn_s_setprio(1);
#pragma unroll
    for (int f = 0; f < 4; ++f)
#pragma unroll
      for (int g = 0; g < 2; ++g)
        acc[f][g] = __builtin_amdgcn_mfma_f32_16x16x32_bf16(af[f], bfr[g], acc[f][g], 0, 0, 0);
    __builtin_amdgcn_s_setprio(0);
  }

#pragma unroll
  for (int f = 0; f < 4; ++f) {
#pragma unroll
    for (int g = 0; g < 2; ++g) {
#pragma unroll
      for (int r = 0; r < 4; ++r) {
        int row = bm + wm4 * 64 + f * 16 + lg * 4 + r;
        int col = bn + wn2 * 32 + g * 16 + lrow;
        psum[(size_t)row * 1024 + col] = __float2bfloat16(acc[f][g][r]);
      }
    }
  }
}

// ======== reduce: out = x2 + b2 + p0 + p1 ========
__global__ __launch_bounds__(256) void reduce_out_kernel(
    const float* __restrict__ x2, const float* __restrict__ b2,
    const bf16* __restrict__ p0, const bf16* __restrict__ p1,
    float* __restrict__ out) {
  int i = blockIdx.x * 256 + threadIdx.x;
  float4 xv = reinterpret_cast<const float4*>(x2)[i];
  ushort4 a = reinterpret_cast<const ushort4*>(p0)[i];
  ushort4 b = reinterpret_cast<const ushort4*>(p1)[i];
  float4 bias = reinterpret_cast<const float4*>(b2)[i & 255];
  float4 o;
  o.x = xv.x + bias.x + bf2f(a.x) + bf2f(b.x);
  o.y = xv.y + bias.y + bf2f(a.y) + bf2f(b.y);
  o.z = xv.z + bias.z + bf2f(a.z) + bf2f(b.z);
  o.w = xv.w + bias.w + bf2f(a.w) + bf2f(b.w);
  reinterpret_cast<float4*>(out)[i] = o;
}

// ======== 8-wave 256x64 GEMM, BK=32, R=3 ring (O projection) ========
__global__ __launch_bounds__(512, 4) void gemm_o_kernel(
    const bf16* __restrict__ A, const bf16* __restrict__ Bt,
    int M, int N, int K,
    const float* __restrict__ bias0,
    const float* __restrict__ resid,
    float* __restrict__ out_f) {
  constexpr int R = 3;
  __shared__ bf16 AS[R][256 * 32];
  __shared__ bf16 BS[R][64 * 32];
  int tid = threadIdx.x;
  int wid = tid >> 6, lane = tid & 63;
  int wm4 = wid >> 1, wn2 = wid & 1;
  int lrow = lane & 15, lg = lane >> 4;
  int nwg = gridDim.x * gridDim.y;
  int lin = blockIdx.y * gridDim.x + blockIdx.x;
  int swz = (lin & 7) * (nwg >> 3) + (lin >> 3);
  int bxi = swz % gridDim.x, byi = swz / gridDim.x;
  int bm = byi * 256, bn = bxi * 64;
  int srow = tid >> 2;
  int sg = (tid & 3) ^ ((tid >> 3) & 3);
  const bf16* Asrc = A  + (size_t)bm * K + sg * 8;
  const bf16* Bsrc = Bt + (size_t)bn * K + sg * 8;
  f32x4 acc[4][2] = {};
  const int NT = K / 32;

  auto stage = [&](int t, int slot) {
    int k0 = t * 32;
#pragma unroll
    for (int j = 0; j < 2; ++j) {
      int row = j * 128 + srow;
      gload_lds16(Asrc + (size_t)row * K + k0, &AS[slot][(j * 512 + tid) * 8]);
    }
    if (wid < 4)
      gload_lds16(Bsrc + (size_t)srow * K + k0, &BS[slot][tid * 8]);
  };

  int sw = (lg ^ ((lrow >> 1) & 3)) << 4;
  stage(0, 0);
  stage(1, 1);
  int rslot = 0, wslot = 2;
  for (int t = 0; t < NT; ++t) {
    if (t < NT - 1) {
      if (wid < 4) vwait<3>(); else vwait<2>();
    } else {
      vwait<0>();
    }
    __builtin_amdgcn_s_barrier();
    const char* as = (const char*)AS[rslot];
    const char* bs = (const char*)BS[rslot];
    bf16x8 af[4], bfr[2];
#pragma unroll
    for (int f = 0; f < 4; ++f)
      af[f] = *reinterpret_cast<const bf16x8*>(as + (wm4 * 64 + f * 16 + lrow) * 64 + sw);
#pragma unroll
    for (int g = 0; g < 2; ++g)
      bfr[g] = *reinterpret_cast<const bf16x8*>(bs + (wn2 * 32 + g * 16 + lrow) * 64 + sw);
    if (t + 2 < NT) stage(t + 2, wslot);
    __builtin_amdgcn_s_setprio(1);
#pragma unroll
    for (int f = 0; f < 4; ++f)
#pragma unroll
      for (int g = 0; g < 2; ++g)
        acc[f][g] = __builtin_amdgcn_mfma_f32_16x16x32_bf16(af[f], bfr[g], acc[f][g], 0, 0, 0);
    __builtin_amdgcn_s_setprio(0);
    rslot = (rslot == R - 1) ? 0 : rslot + 1;
    wslot = (wslot == R - 1) ? 0 : wslot + 1;
  }

#pragma unroll
  for (int f = 0; f < 4; ++f) {
#pragma unroll
    for (int g = 0; g < 2; ++g) {
#pragma unroll
      for (int r = 0; r < 4; ++r) {
        int row = bm + wm4 * 64 + f * 16 + lg * 4 + r;
        int col = bn + wn2 * 32 + g * 16 + lrow;
        out_f[(size_t)row * N + col] = resid[(size_t)row * N + col] + acc[f][g][r] + bias0[col];
      }
    }
  }
}

// ---------------- flash attention: 16 waves, 256 q-rows/block ----------------
#define KVB 64
__global__ __launch_bounds__(1024) void attn_kernel(
    const bf16* __restrict__ q, const bf16* __restrict__ k,
    const bf16* __restrict__ vt, const unsigned* __restrict__ mbits,
    bf16* __restrict__ ctx) {
  __shared__ bf16 Kt[2][KVB * 64];
  __shared__ bf16 Vt[2][KVB * 64];
  __shared__ bf16 P[16][16 * 64];
  int tid = threadIdx.x, wid = tid >> 6, lane = tid & 63;
  int blk = (blockIdx.x & 7) * 32 + (blockIdx.x >> 3);  // XCD swizzle, 256 blocks
  int qblk = blk & 3, h = (blk >> 2) & 15, b = blk >> 6;
  int qs = qblk * 256 + wid * 16;
  int lrow = lane & 15, lg = lane >> 4;

  size_t qoff = ((size_t)(b * SEQ + qs + lrow)) * D_MODEL + h * HDIM;
  bf16x8 qa0 = *reinterpret_cast<const bf16x8*>(q + qoff + lg * 8);
  bf16x8 qa1 = *reinterpret_cast<const bf16x8*>(q + qoff + 32 + lg * 8);

  float ps[4] = {0.f, 0.f, 0.f, 0.f};
  f32x4 O[4] = {};
  const unsigned* mb = mbits + ((size_t)(b * SEQ + qs + lg * 4)) * 32;
  bf16* Pw = P[wid];

  int rr = lane >> 3;
  int sg8 = (lane & 7) ^ rr;
  const bf16* kb_src = k + ((size_t)b * SEQ) * D_MODEL + h * HDIM + sg8 * 8;
  const bf16* vb_src = vt + ((size_t)(b * D_MODEL + h * HDIM)) * SEQ + sg8 * 8;

#define STAGE(KT2, BUF)                                                          \
  {                                                                              \
    int ks2 = (KT2) * KVB;                                                       \
    if (wid < 8) {                                                               \
      gload_lds16(kb_src + (size_t)(ks2 + wid * 8 + rr) * D_MODEL,               \
                  &Kt[BUF][wid * 512]);                                          \
    } else {                                                                     \
      gload_lds16(vb_src + (size_t)((wid - 8) * 8 + rr) * SEQ + ks2,             \
                  &Vt[BUF][(wid - 8) * 512]);                                    \
    }                                                                            \
  }

  STAGE(0, 0);
  for (int kt = 0; kt < SEQ / KVB; ++kt) {
    int cur = kt & 1;
    __syncthreads();
    if (kt < SEQ / KVB - 1) STAGE(kt + 1, cur ^ 1);

    f32x4 sc[4];
#pragma unroll
    for (int c = 0; c < 4; ++c) {
      int krow = c * 16 + lrow;
      const char* kp = (const char*)&Kt[cur][krow * 64];
      bf16x8 kb0 = *reinterpret_cast<const bf16x8*>(kp + ((lg ^ (krow & 7)) << 4));
      bf16x8 kb1 = *reinterpret_cast<const bf16x8*>(kp + ((((lg + 4) & 7) ^ (krow & 7)) << 4));
      f32x4 z = {0.f, 0.f, 0.f, 0.f};
      sc[c] = __builtin_amdgcn_mfma_f32_16x16x32_bf16(qa0, kb0, z, 0, 0, 0);
      sc[c] = __builtin_amdgcn_mfma_f32_16x16x32_bf16(qa1, kb1, sc[c], 0, 0, 0);
    }

#pragma unroll
    for (int r = 0; r < 4; ++r) {
      uint2 w = *reinterpret_cast<const uint2*>(mb + (size_t)r * 32 + kt * 2);
      int prow = lg * 4 + r;
      char* pb = (char*)Pw + prow * 128;
#pragma unroll
      for (int c = 0; c < 4; ++c) {
        unsigned wsel = (c >= 2) ? w.y : w.x;
        unsigned keep = (wsel >> ((c & 1) * 16 + lrow)) & 1u;
        float p = keep ? __expf(sc[c][r]) : 0.f;
        ps[r] += p;
        int pcol = c * 16 + lrow;
        *(__bf16*)(pb + (((pcol >> 3) ^ (prow & 7)) << 4) + (pcol & 7) * 2) =
            __float2bfloat16(p);
      }
    }

    const char* pbase = (const char*)Pw + lrow * 128;
    bf16x8 pa0 = *reinterpret_cast<const bf16x8*>(pbase + ((lg ^ (lrow & 7)) << 4));
    bf16x8 pa1 = *reinterpret_cast<const bf16x8*>(pbase + ((((lg + 4) & 7) ^ (lrow & 7)) << 4));
#pragma unroll
    for (int nb = 0; nb < 4; ++nb) {
      int vrow = nb * 16 + lrow;
      const char* vp = (const char*)&Vt[cur][vrow * 64];
      bf16x8 vb0 = *reinterpret_cast<const bf16x8*>(vp + ((lg ^ (vrow & 7)) << 4));
      bf16x8 vb1 = *reinterpret_cast<const bf16x8*>(vp + ((((lg + 4) & 7) ^ (vrow & 7)) << 4));
      O[nb] = __builtin_amdgcn_mfma_f32_16x16x32_bf16(pa0, vb0, O[nb], 0, 0, 0);
      O[nb] = __builtin_amdgcn_mfma_f32_16x16x32_bf16(pa1, vb1, O[nb], 0, 0, 0);
    }
  }
#undef STAGE

#pragma unroll
  for (int o = 1; o < 16; o <<= 1)
#pragma unroll
    for (int r = 0; r < 4; ++r) ps[r] += __shfl_xor(ps[r], o);
#pragma unroll
  for (int nb = 0; nb < 4; ++nb)
#pragma unroll
    for (int r = 0; r < 4; ++r) {
      int qg = qs + lg * 4 + r;
      ctx[((size_t)(b * SEQ + qg)) * D_MODEL + h * HDIM + nb * 16 + lrow] =
          __float2bfloat16(O[nb][r] / ps[r]);
    }
}

// ---------------- host launch ----------------
extern "C" void kernel_launch(void* const* d_in, const int* in_sizes, int n_in,
                              void* d_out, int out_size, void* d_ws, size_t ws_size,
                              hipStream_t stream) {
  const float* x        = (const float*)d_in[0];
  const float* mask     = (const float*)d_in[2];
  const float* ln1_g    = (const float*)d_in[3];
  const float* ln1_b    = (const float*)d_in[4];
  const float* Wq       = (const float*)d_in[5];
  const float* bq       = (const float*)d_in[6];
  const float* Wk       = (const float*)d_in[7];
  const float* bk       = (const float*)d_in[8];
  const float* Wv       = (const float*)d_in[9];
  const float* bv       = (const float*)d_in[10];
  const float* Wo       = (const float*)d_in[11];
  const float* bo       = (const float*)d_in[12];
  const float* ln2_g    = (const float*)d_in[13];
  const float* ln2_b    = (const float*)d_in[14];
  const float* W1       = (const float*)d_in[15];
  const float* b1       = (const float*)d_in[16];
  const float* W2       = (const float*)d_in[17];
  const float* b2       = (const float*)d_in[18];
  float* out            = (float*)d_out;

  char* w = (char*)d_ws;
  const size_t MB = 1u << 20;
  bf16*     y      = (bf16*)(w + 0);          // 8MB  [4096,1024]
  bf16*     qb     = (bf16*)(w + 8 * MB);     // 8MB
  bf16*     kb     = (bf16*)(w + 16 * MB);    // 8MB
  bf16*     vt     = (bf16*)(w + 24 * MB);    // 8MB  [B][D][S]
  bf16*     hbuf   = (bf16*)(w + 0);          // 32MB (aliases y/q/k/vt, all dead)
  bf16*     Wqkv_t = (bf16*)(w + 32 * MB);    // 6MB
  bf16*     Wo_t   = (bf16*)(w + 38 * MB);    // 2MB
  bf16*     W1_t   = (bf16*)(w + 40 * MB);    // 8MB
  bf16*     W2_t   = (bf16*)(w + 48 * MB);    // 8MB
  bf16*     ctx    = (bf16*)(w + 56 * MB);    // 8MB
  float*    x2     = (float*)(w + 64 * MB);   // 16MB (written after attn)
  unsigned* mbits  = (unsigned*)(w + 64 * MB);// 512KB (dead once attn done)
  bf16*     y2     = (bf16*)(w + 80 * MB);    // 8MB
  bf16*     psum0  = (bf16*)(w + 56 * MB);    // 8MB (ctx region, dead after O)
  bf16*     psum1  = (bf16*)(w + 80 * MB);    // 8MB (y2 region, dead after GELU)
  (void)in_sizes; (void)n_in; (void)out_size; (void)ws_size;

  prep_kernel<<<13312, 1024, 0, stream>>>(Wq, Wk, Wv, Wo, W1, W2, mask,
                                          Wqkv_t, Wo_t, W1_t, W2_t, mbits);

  layernorm_kernel<<<4096, 256, 0, stream>>>(x, ln1_g, ln1_b, y);

  gemm8p_kernel<MODE_QKV><<<dim3(12, 16), 512, 0, stream>>>(
      y, Wqkv_t, 4096, 3072, 1024, bq, bk, bv, qb, kb, vt, nullptr);

  attn_kernel<<<256, 1024, 0, stream>>>(qb, kb, vt, mbits, ctx);

  gemm_o_kernel<<<dim3(16, 16), 512, 0, stream>>>(
      ctx, Wo_t, 4096, 1024, 1024, bo, x, x2);

  layernorm_kernel<<<4096, 256, 0, stream>>>(x2, ln2_g, ln2_b, y2);

  gemm8p_kernel<MODE_GELU><<<dim3(16, 16), 512, 0, stream>>>(
      y2, W1_t, 4096, 4096, 1024, b1, nullptr, nullptr,
      nullptr, nullptr, nullptr, hbuf);

  gemm_out_split_kernel<<<dim3(16, 32), 512, 0, stream>>>(
      hbuf, W2_t, 4096, psum0, psum1);

  reduce_out_kernel<<<4096, 256, 0, stream>>>(x2, b2, psum0, psum1, out);
}

// Round 21
// 239.456 us; speedup vs baseline: 1.1751x; 1.1751x over previous
//
#include <hip/hip_runtime.h>
#include <hip/hip_bf16.h>
#include <math.h>

typedef __attribute__((ext_vector_type(8))) __bf16 bf16x8;
typedef __attribute__((ext_vector_type(4))) float f32x4;
typedef __hip_bfloat16 bf16;

#define D_MODEL 1024
#define F_FFN   4096
#define NHEAD   16
#define HDIM    64
#define SEQ     1024
#define BATCH   4

static __device__ __forceinline__ unsigned short bf_bits(bf16 h) {
  return __builtin_bit_cast(unsigned short, h);
}
static __device__ __forceinline__ float bf2f(unsigned short u) {
  unsigned v = (unsigned)u << 16;
  return __builtin_bit_cast(float, v);
}

template <int N>
static __device__ __forceinline__ void vwait() {
  asm volatile("s_waitcnt vmcnt(%0)" :: "n"(N) : "memory");
}

static __device__ __forceinline__ void gload_lds16(const bf16* src, bf16* dst) {
  __builtin_amdgcn_global_load_lds(
      (const __attribute__((address_space(1))) void*)src,
      (__attribute__((address_space(3))) void*)dst, 16, 0, 0);
}

// fast GELU: tanh form, |err| vs erf <= ~3e-4 absolute
static __device__ __forceinline__ float gelu_fast(float x) {
  float u = x * (0.7978845608f + 0.0356774081f * x * x);
  u = fminf(u, 15.f);
  float e = __expf(2.f * u);
  return 0.5f * x * (1.f + (e - 1.f) / (e + 1.f));
}

// ---------------- fused prep: 6 weight transposes + maskbits ----------------
__global__ __launch_bounds__(1024) void prep_kernel(
    const float* __restrict__ Wq, const float* __restrict__ Wk,
    const float* __restrict__ Wv, const float* __restrict__ Wo,
    const float* __restrict__ W1, const float* __restrict__ W2,
    const float* __restrict__ mask,
    bf16* __restrict__ Wqkv_t, bf16* __restrict__ Wo_t,
    bf16* __restrict__ W1_t, bf16* __restrict__ W2_t,
    unsigned* __restrict__ mbits) {
  __shared__ float tile[32][33];
  int bid = blockIdx.x;
  int tid = threadIdx.x;
  if (bid < 12288) {
    const float* W; bf16* Wt; int K, N, tx32, ty32;
    if (bid < 4096) {
      int w = bid >> 10;
      W  = (w == 0) ? Wq : (w == 1) ? Wk : (w == 2) ? Wv : Wo;
      Wt = (w < 3) ? Wqkv_t + (size_t)w * 1024 * 1024 : Wo_t;
      K = 1024; N = 1024;
      int t = bid & 1023; tx32 = t & 31; ty32 = t >> 5;
    } else if (bid < 8192) {
      W = W1; Wt = W1_t; K = 1024; N = 4096;
      int t = bid - 4096; tx32 = t & 127; ty32 = t >> 7;
    } else {
      W = W2; Wt = W2_t; K = 4096; N = 1024;
      int t = bid - 8192; tx32 = t & 31; ty32 = t >> 5;
    }
    int nb = tx32 * 32, kb = ty32 * 32;
    int tx = tid & 31, ty = tid >> 5;
    tile[ty][tx] = W[(size_t)(kb + ty) * N + nb + tx];
    __syncthreads();
    Wt[(size_t)(nb + ty) * K + kb + tx] = __float2bfloat16(tile[tx][ty]);
  } else {
    int gw = ((bid - 12288) * 1024 + tid) >> 6;
    int lane = tid & 63;
    const float4 m = reinterpret_cast<const float4*>(mask)[(size_t)gw * 64 + lane];
    unsigned long long b0 = __ballot(m.x > 0.f);
    unsigned long long b1 = __ballot(m.y > 0.f);
    unsigned long long b2 = __ballot(m.z > 0.f);
    unsigned long long b3 = __ballot(m.w > 0.f);
    if (lane < 8) {
      unsigned v = 0;
#pragma unroll
      for (int i = 0; i < 8; ++i) {
        int srcl = lane * 8 + i;
        v |= (((unsigned)(b0 >> srcl) & 1u) << (i * 4 + 0));
        v |= (((unsigned)(b1 >> srcl) & 1u) << (i * 4 + 1));
        v |= (((unsigned)(b2 >> srcl) & 1u) << (i * 4 + 2));
        v |= (((unsigned)(b3 >> srcl) & 1u) << (i * 4 + 3));
      }
      mbits[(size_t)gw * 8 + lane] = v;
    }
  }
}

// ---------------- LayerNorm: fp32 in -> bf16 out ----------------
__global__ __launch_bounds__(256) void layernorm_kernel(
    const float* __restrict__ x, const float* __restrict__ g,
    const float* __restrict__ bt, bf16* __restrict__ y) {
  int row = blockIdx.x;
  int tid = threadIdx.x;
  const float* xr = x + (size_t)row * D_MODEL;
  float4 v = reinterpret_cast<const float4*>(xr)[tid];
  float s  = v.x + v.y + v.z + v.w;
  float s2 = v.x * v.x + v.y * v.y + v.z * v.z + v.w * v.w;
  for (int o = 32; o; o >>= 1) { s += __shfl_xor(s, o); s2 += __shfl_xor(s2, o); }
  __shared__ float r1[4], r2[4];
  int wid = tid >> 6, lane = tid & 63;
  if (lane == 0) { r1[wid] = s; r2[wid] = s2; }
  __syncthreads();
  float tot  = r1[0] + r1[1] + r1[2] + r1[3];
  float tot2 = r2[0] + r2[1] + r2[2] + r2[3];
  float mean = tot * (1.f / D_MODEL);
  float var  = tot2 * (1.f / D_MODEL) - mean * mean;
  float rstd = rsqrtf(var + 1e-5f);
  float4 gg = reinterpret_cast<const float4*>(g)[tid];
  float4 bb = reinterpret_cast<const float4*>(bt)[tid];
  ushort4 o;
  o.x = bf_bits(__float2bfloat16((v.x - mean) * rstd * gg.x + bb.x));
  o.y = bf_bits(__float2bfloat16((v.y - mean) * rstd * gg.y + bb.y));
  o.z = bf_bits(__float2bfloat16((v.z - mean) * rstd * gg.z + bb.z));
  o.w = bf_bits(__float2bfloat16((v.w - mean) * rstd * gg.w + bb.w));
  reinterpret_cast<ushort4*>(y + (size_t)row * D_MODEL)[tid] = o;
}

enum { MODE_QKV = 0, MODE_O = 1 };

// ======== 16-wave 256x256, BK=32, R=4 ring, counted lead-2 (GELU) ========
__global__ __launch_bounds__(1024, 1) void gemm256sq_gelu_kernel(
    const bf16* __restrict__ A, const bf16* __restrict__ Bt,
    int M, int N, int K,
    const float* __restrict__ bias0, bf16* __restrict__ out_bf) {
  constexpr int R = 4;
  __shared__ bf16 AS[R][256 * 32];
  __shared__ bf16 BS[R][256 * 32];
  int tid = threadIdx.x;
  int wid = tid >> 6, lane = tid & 63;
  int wm4 = wid >> 2, wn4 = wid & 3;
  int lrow = lane & 15, lg = lane >> 4;
  int nwg = gridDim.x * gridDim.y;
  int lin = blockIdx.y * gridDim.x + blockIdx.x;
  int swz = (lin & 7) * (nwg >> 3) + (lin >> 3);
  int bxi = swz % gridDim.x, byi = swz / gridDim.x;
  int bm = byi * 256, bn = bxi * 256;
  int srow = tid >> 2;
  int sg = (tid & 3) ^ ((tid >> 3) & 3);
  const bf16* Asrc = A  + (size_t)bm * K + sg * 8;
  const bf16* Bsrc = Bt + (size_t)bn * K + sg * 8;
  f32x4 acc[4][4] = {};
  const int NT = K / 32;

  auto stage = [&](int t) {
    int slot = t & 3;
    int k0 = t * 32;
    gload_lds16(Asrc + (size_t)srow * K + k0, &AS[slot][tid * 8]);
    gload_lds16(Bsrc + (size_t)srow * K + k0, &BS[slot][tid * 8]);
  };

  int sw = (lg ^ ((lrow >> 1) & 3)) << 4;
  stage(0); stage(1); stage(2);
  for (int t = 0; t < NT; ++t) {
    if (t < NT - 2)       vwait<4>();
    else if (t == NT - 2) vwait<2>();
    else                  vwait<0>();
    __builtin_amdgcn_s_barrier();
    int slot = t & 3;
    const char* as = (const char*)AS[slot];
    const char* bs = (const char*)BS[slot];
    bf16x8 af[4], bfr[4];
#pragma unroll
    for (int f = 0; f < 4; ++f)
      af[f] = *reinterpret_cast<const bf16x8*>(as + (wm4 * 64 + f * 16 + lrow) * 64 + sw);
#pragma unroll
    for (int g = 0; g < 4; ++g)
      bfr[g] = *reinterpret_cast<const bf16x8*>(bs + (wn4 * 64 + g * 16 + lrow) * 64 + sw);
    if (t + 3 < NT) stage(t + 3);
    __builtin_amdgcn_s_setprio(1);
#pragma unroll
    for (int f = 0; f < 4; ++f)
#pragma unroll
      for (int g = 0; g < 4; ++g)
        acc[f][g] = __builtin_amdgcn_mfma_f32_16x16x32_bf16(af[f], bfr[g], acc[f][g], 0, 0, 0);
    __builtin_amdgcn_s_setprio(0);
  }

#pragma unroll
  for (int f = 0; f < 4; ++f) {
#pragma unroll
    for (int g = 0; g < 4; ++g) {
#pragma unroll
      for (int r = 0; r < 4; ++r) {
        int row = bm + wm4 * 64 + f * 16 + lg * 4 + r;
        int col = bn + wn4 * 64 + g * 16 + lrow;
        float tv = acc[f][g][r] + bias0[col];
        out_bf[(size_t)row * N + col] = __float2bfloat16(gelu_fast(tv));
      }
    }
  }
}

// ======== OUT split-K=2: 8-wave 256x64, BK=32, R=4 ring, lead-2 ========
__global__ __launch_bounds__(512, 2) void gemm_out_split_kernel(
    const bf16* __restrict__ A, const bf16* __restrict__ Bt, int K,
    bf16* __restrict__ psum0, bf16* __restrict__ psum1) {
  constexpr int R = 4;
  __shared__ bf16 AS[R][256 * 32];
  __shared__ bf16 BS[R][64 * 32];
  int tid = threadIdx.x;
  int wid = tid >> 6, lane = tid & 63;
  int wm4 = wid >> 1, wn2 = wid & 1;
  int lrow = lane & 15, lg = lane >> 4;
  int nwg = gridDim.x * gridDim.y;       // 512
  int lin = blockIdx.y * gridDim.x + blockIdx.x;
  int swz = (lin & 7) * (nwg >> 3) + (lin >> 3);
  int bxi = swz & 15;
  int rest = swz >> 4;
  int byi = rest & 15, z = rest >> 4;
  int bm = byi * 256, bn = bxi * 64;
  int kbeg = z * 2048;
  bf16* psum = z ? psum1 : psum0;
  int srow = tid >> 2;
  int sg = (tid & 3) ^ ((tid >> 3) & 3);
  const bf16* Asrc = A  + (size_t)bm * K + kbeg + sg * 8;
  const bf16* Bsrc = Bt + (size_t)bn * K + kbeg + sg * 8;
  f32x4 acc[4][2] = {};
  const int NT = 2048 / 32;

  auto stage = [&](int t) {
    int slot = t & 3;
    int k0 = t * 32;
#pragma unroll
    for (int j = 0; j < 2; ++j) {
      int row = j * 128 + srow;
      gload_lds16(Asrc + (size_t)row * K + k0, &AS[slot][(j * 512 + tid) * 8]);
    }
    if (wid < 4)
      gload_lds16(Bsrc + (size_t)srow * K + k0, &BS[slot][tid * 8]);
  };

  int sw = (lg ^ ((lrow >> 1) & 3)) << 4;
  stage(0); stage(1); stage(2);
  for (int t = 0; t < NT; ++t) {
    if (t < NT - 2) {
      if (wid < 4) vwait<6>(); else vwait<4>();
    } else if (t == NT - 2) {
      if (wid < 4) vwait<3>(); else vwait<2>();
    } else {
      vwait<0>();
    }
    __builtin_amdgcn_s_barrier();
    int slot = t & 3;
    const char* as = (const char*)AS[slot];
    const char* bs = (const char*)BS[slot];
    bf16x8 af[4], bfr[2];
#pragma unroll
    for (int f = 0; f < 4; ++f)
      af[f] = *reinterpret_cast<const bf16x8*>(as + (wm4 * 64 + f * 16 + lrow) * 64 + sw);
#pragma unroll
    for (int g = 0; g < 2; ++g)
      bfr[g] = *reinterpret_cast<const bf16x8*>(bs + (wn2 * 32 + g * 16 + lrow) * 64 + sw);
    if (t + 3 < NT) stage(t + 3);
    __builtin_amdgcn_s_setprio(1);
#pragma unroll
    for (int f = 0; f < 4; ++f)
#pragma unroll
      for (int g = 0; g < 2; ++g)
        acc[f][g] = __builtin_amdgcn_mfma_f32_16x16x32_bf16(af[f], bfr[g], acc[f][g], 0, 0, 0);
    __builtin_amdgcn_s_setprio(0);
  }

#pragma unroll
  for (int f = 0; f < 4; ++f) {
#pragma unroll
    for (int g = 0; g < 2; ++g) {
#pragma unroll
      for (int r = 0; r < 4; ++r) {
        int row = bm + wm4 * 64 + f * 16 + lg * 4 + r;
        int col = bn + wn2 * 32 + g * 16 + lrow;
        psum[(size_t)row * 1024 + col] = __float2bfloat16(acc[f][g][r]);
      }
    }
  }
}

// ======== reduce: out = x2 + b2 + p0 + p1 ========
__global__ __launch_bounds__(256) void reduce_out_kernel(
    const float* __restrict__ x2, const float* __restrict__ b2,
    const bf16* __restrict__ p0, const bf16* __restrict__ p1,
    float* __restrict__ out) {
  int i = blockIdx.x * 256 + threadIdx.x;
  float4 xv = reinterpret_cast<const float4*>(x2)[i];
  ushort4 a = reinterpret_cast<const ushort4*>(p0)[i];
  ushort4 b = reinterpret_cast<const ushort4*>(p1)[i];
  float4 bias = reinterpret_cast<const float4*>(b2)[i & 255];
  float4 o;
  o.x = xv.x + bias.x + bf2f(a.x) + bf2f(b.x);
  o.y = xv.y + bias.y + bf2f(a.y) + bf2f(b.y);
  o.z = xv.z + bias.z + bf2f(a.z) + bf2f(b.z);
  o.w = xv.w + bias.w + bf2f(a.w) + bf2f(b.w);
  reinterpret_cast<float4*>(out)[i] = o;
}

// ======== unified 8-wave 256xTN GEMM, BK=32, R=3 ring (QKV + O) ========
template <int MODE, int TN>
__global__ __launch_bounds__(512, 4) void gemm256_kernel(
    const bf16* __restrict__ A, const bf16* __restrict__ Bt,
    int M, int N, int K,
    const float* __restrict__ bias0, const float* __restrict__ bias1,
    const float* __restrict__ bias2,
    const float* __restrict__ resid,
    bf16* __restrict__ out_q, bf16* __restrict__ out_k, bf16* __restrict__ out_vt,
    float* __restrict__ out_f) {
  constexpr int R = 3;
  constexpr int NF = TN / 32;
  __shared__ bf16 AS[R][256 * 32];
  __shared__ bf16 BS[R][TN * 32];
  int tid = threadIdx.x;
  int wid = tid >> 6, lane = tid & 63;
  int wm4 = wid >> 1, wn2 = wid & 1;
  int lrow = lane & 15, lg = lane >> 4;
  int nwg = gridDim.x * gridDim.y;
  int lin = blockIdx.y * gridDim.x + blockIdx.x;
  int swz = (lin & 7) * (nwg >> 3) + (lin >> 3);
  int bxi = swz % gridDim.x, byi = swz / gridDim.x;
  int bm = byi * 256, bn = bxi * TN;
  int srow = tid >> 2;
  int sg = (tid & 3) ^ ((tid >> 3) & 3);
  const bf16* Asrc = A  + (size_t)bm * K + sg * 8;
  const bf16* Bsrc = Bt + (size_t)bn * K + sg * 8;
  f32x4 acc[4][NF] = {};
  const int NT = K / 32;

  auto stage = [&](int t, int slot) {
    int k0 = t * 32;
#pragma unroll
    for (int j = 0; j < 2; ++j) {
      int row = j * 128 + srow;
      gload_lds16(Asrc + (size_t)row * K + k0, &AS[slot][(j * 512 + tid) * 8]);
    }
    if (TN == 128) {
      gload_lds16(Bsrc + (size_t)srow * K + k0, &BS[slot][tid * 8]);
    } else {
      if (wid < 4)
        gload_lds16(Bsrc + (size_t)srow * K + k0, &BS[slot][tid * 8]);
    }
  };

  int sw = (lg ^ ((lrow >> 1) & 3)) << 4;
  stage(0, 0);
  stage(1, 1);
  int rslot = 0, wslot = 2;
  for (int t = 0; t < NT; ++t) {
    if (t < NT - 1) {
      if (TN == 128) { vwait<3>(); }
      else { if (wid < 4) vwait<3>(); else vwait<2>(); }
    } else {
      vwait<0>();
    }
    __builtin_amdgcn_s_barrier();
    const char* as = (const char*)AS[rslot];
    const char* bs = (const char*)BS[rslot];
    bf16x8 af[4], bfr[NF];
#pragma unroll
    for (int f = 0; f < 4; ++f)
      af[f] = *reinterpret_cast<const bf16x8*>(as + (wm4 * 64 + f * 16 + lrow) * 64 + sw);
#pragma unroll
    for (int g = 0; g < NF; ++g)
      bfr[g] = *reinterpret_cast<const bf16x8*>(bs + (wn2 * (TN / 2) + g * 16 + lrow) * 64 + sw);
    if (t + 2 < NT) stage(t + 2, wslot);
    __builtin_amdgcn_s_setprio(1);
#pragma unroll
    for (int f = 0; f < 4; ++f)
#pragma unroll
      for (int g = 0; g < NF; ++g)
        acc[f][g] = __builtin_amdgcn_mfma_f32_16x16x32_bf16(af[f], bfr[g], acc[f][g], 0, 0, 0);
    __builtin_amdgcn_s_setprio(0);
    rslot = (rslot == R - 1) ? 0 : rslot + 1;
    wslot = (wslot == R - 1) ? 0 : wslot + 1;
  }

#pragma unroll
  for (int f = 0; f < 4; ++f) {
#pragma unroll
    for (int g = 0; g < NF; ++g) {
#pragma unroll
      for (int r = 0; r < 4; ++r) {
        int row = bm + wm4 * 64 + f * 16 + lg * 4 + r;
        int col = bn + wn2 * (TN / 2) + g * 16 + lrow;
        float v = acc[f][g][r];
        if (MODE == MODE_QKV) {
          if (col < 1024) {
            out_q[(size_t)row * 1024 + col] = __float2bfloat16((v + bias0[col]) * 0.125f);
          } else if (col < 2048) {
            out_k[(size_t)row * 1024 + (col - 1024)] = __float2bfloat16(v + bias1[col - 1024]);
          } else {
            int d = col - 2048;
            int b = row >> 10;
            int s = row & 1023;
            out_vt[((size_t)(b << 10) + d) * 1024 + s] = __float2bfloat16(v + bias2[d]);
          }
        } else {  // MODE_O
          out_f[(size_t)row * N + col] = resid[(size_t)row * N + col] + v + bias0[col];
        }
      }
    }
  }
}

// ---------------- flash attention: 16 waves, 256 q-rows/block ----------------
#define KVB 64
__global__ __launch_bounds__(1024) void attn_kernel(
    const bf16* __restrict__ q, const bf16* __restrict__ k,
    const bf16* __restrict__ vt, const unsigned* __restrict__ mbits,
    bf16* __restrict__ ctx) {
  __shared__ bf16 Kt[2][KVB * 64];
  __shared__ bf16 Vt[2][KVB * 64];
  __shared__ bf16 P[16][16 * 64];
  int tid = threadIdx.x, wid = tid >> 6, lane = tid & 63;
  int blk = (blockIdx.x & 7) * 32 + (blockIdx.x >> 3);  // XCD swizzle, 256 blocks
  int qblk = blk & 3, h = (blk >> 2) & 15, b = blk >> 6;
  int qs = qblk * 256 + wid * 16;
  int lrow = lane & 15, lg = lane >> 4;

  size_t qoff = ((size_t)(b * SEQ + qs + lrow)) * D_MODEL + h * HDIM;
  bf16x8 qa0 = *reinterpret_cast<const bf16x8*>(q + qoff + lg * 8);
  bf16x8 qa1 = *reinterpret_cast<const bf16x8*>(q + qoff + 32 + lg * 8);

  float ps[4] = {0.f, 0.f, 0.f, 0.f};
  f32x4 O[4] = {};
  const unsigned* mb = mbits + ((size_t)(b * SEQ + qs + lg * 4)) * 32;
  bf16* Pw = P[wid];

  int rr = lane >> 3;
  int sg8 = (lane & 7) ^ rr;
  const bf16* kb_src = k + ((size_t)b * SEQ) * D_MODEL + h * HDIM + sg8 * 8;
  const bf16* vb_src = vt + ((size_t)(b * D_MODEL + h * HDIM)) * SEQ + sg8 * 8;

#define STAGE(KT2, BUF)                                                          \
  {                                                                              \
    int ks2 = (KT2) * KVB;                                                       \
    if (wid < 8) {                                                               \
      gload_lds16(kb_src + (size_t)(ks2 + wid * 8 + rr) * D_MODEL,               \
                  &Kt[BUF][wid * 512]);                                          \
    } else {                                                                     \
      gload_lds16(vb_src + (size_t)((wid - 8) * 8 + rr) * SEQ + ks2,             \
                  &Vt[BUF][(wid - 8) * 512]);                                    \
    }                                                                            \
  }

  STAGE(0, 0);
  for (int kt = 0; kt < SEQ / KVB; ++kt) {
    int cur = kt & 1;
    __syncthreads();
    if (kt < SEQ / KVB - 1) STAGE(kt + 1, cur ^ 1);

    f32x4 sc[4];
#pragma unroll
    for (int c = 0; c < 4; ++c) {
      int krow = c * 16 + lrow;
      const char* kp = (const char*)&Kt[cur][krow * 64];
      bf16x8 kb0 = *reinterpret_cast<const bf16x8*>(kp + ((lg ^ (krow & 7)) << 4));
      bf16x8 kb1 = *reinterpret_cast<const bf16x8*>(kp + ((((lg + 4) & 7) ^ (krow & 7)) << 4));
      f32x4 z = {0.f, 0.f, 0.f, 0.f};
      sc[c] = __builtin_amdgcn_mfma_f32_16x16x32_bf16(qa0, kb0, z, 0, 0, 0);
      sc[c] = __builtin_amdgcn_mfma_f32_16x16x32_bf16(qa1, kb1, sc[c], 0, 0, 0);
    }

#pragma unroll
    for (int r = 0; r < 4; ++r) {
      uint2 w = *reinterpret_cast<const uint2*>(mb + (size_t)r * 32 + kt * 2);
      int prow = lg * 4 + r;
      char* pb = (char*)Pw + prow * 128;
#pragma unroll
      for (int c = 0; c < 4; ++c) {
        unsigned wsel = (c >= 2) ? w.y : w.x;
        unsigned keep = (wsel >> ((c & 1) * 16 + lrow)) & 1u;
        float p = keep ? __expf(sc[c][r]) : 0.f;
        ps[r] += p;
        int pcol = c * 16 + lrow;
        *(__bf16*)(pb + (((pcol >> 3) ^ (prow & 7)) << 4) + (pcol & 7) * 2) =
            __float2bfloat16(p);
      }
    }

    const char* pbase = (const char*)Pw + lrow * 128;
    bf16x8 pa0 = *reinterpret_cast<const bf16x8*>(pbase + ((lg ^ (lrow & 7)) << 4));
    bf16x8 pa1 = *reinterpret_cast<const bf16x8*>(pbase + ((((lg + 4) & 7) ^ (lrow & 7)) << 4));
#pragma unroll
    for (int nb = 0; nb < 4; ++nb) {
      int vrow = nb * 16 + lrow;
      const char* vp = (const char*)&Vt[cur][vrow * 64];
      bf16x8 vb0 = *reinterpret_cast<const bf16x8*>(vp + ((lg ^ (vrow & 7)) << 4));
      bf16x8 vb1 = *reinterpret_cast<const bf16x8*>(vp + ((((lg + 4) & 7) ^ (vrow & 7)) << 4));
      O[nb] = __builtin_amdgcn_mfma_f32_16x16x32_bf16(pa0, vb0, O[nb], 0, 0, 0);
      O[nb] = __builtin_amdgcn_mfma_f32_16x16x32_bf16(pa1, vb1, O[nb], 0, 0, 0);
    }
  }
#undef STAGE

#pragma unroll
  for (int o = 1; o < 16; o <<= 1)
#pragma unroll
    for (int r = 0; r < 4; ++r) ps[r] += __shfl_xor(ps[r], o);
#pragma unroll
  for (int nb = 0; nb < 4; ++nb)
#pragma unroll
    for (int r = 0; r < 4; ++r) {
      int qg = qs + lg * 4 + r;
      ctx[((size_t)(b * SEQ + qg)) * D_MODEL + h * HDIM + nb * 16 + lrow] =
          __float2bfloat16(O[nb][r] / ps[r]);
    }
}

// ---------------- host launch ----------------
extern "C" void kernel_launch(void* const* d_in, const int* in_sizes, int n_in,
                              void* d_out, int out_size, void* d_ws, size_t ws_size,
                              hipStream_t stream) {
  const float* x        = (const float*)d_in[0];
  const float* mask     = (const float*)d_in[2];
  const float* ln1_g    = (const float*)d_in[3];
  const float* ln1_b    = (const float*)d_in[4];
  const float* Wq       = (const float*)d_in[5];
  const float* bq       = (const float*)d_in[6];
  const float* Wk       = (const float*)d_in[7];
  const float* bk       = (const float*)d_in[8];
  const float* Wv       = (const float*)d_in[9];
  const float* bv       = (const float*)d_in[10];
  const float* Wo       = (const float*)d_in[11];
  const float* bo       = (const float*)d_in[12];
  const float* ln2_g    = (const float*)d_in[13];
  const float* ln2_b    = (const float*)d_in[14];
  const float* W1       = (const float*)d_in[15];
  const float* b1       = (const float*)d_in[16];
  const float* W2       = (const float*)d_in[17];
  const float* b2       = (const float*)d_in[18];
  float* out            = (float*)d_out;

  char* w = (char*)d_ws;
  const size_t MB = 1u << 20;
  bf16*     y      = (bf16*)(w + 0);          // 8MB  [4096,1024]
  bf16*     qb     = (bf16*)(w + 8 * MB);     // 8MB
  bf16*     kb     = (bf16*)(w + 16 * MB);    // 8MB
  bf16*     vt     = (bf16*)(w + 24 * MB);    // 8MB  [B][D][S]
  bf16*     hbuf   = (bf16*)(w + 0);          // 32MB (aliases y/q/k/vt, all dead)
  bf16*     Wqkv_t = (bf16*)(w + 32 * MB);    // 6MB
  bf16*     Wo_t   = (bf16*)(w + 38 * MB);    // 2MB
  bf16*     W1_t   = (bf16*)(w + 40 * MB);    // 8MB
  bf16*     W2_t   = (bf16*)(w + 48 * MB);    // 8MB
  bf16*     ctx    = (bf16*)(w + 56 * MB);    // 8MB
  float*    x2     = (float*)(w + 64 * MB);   // 16MB (written after attn)
  unsigned* mbits  = (unsigned*)(w + 64 * MB);// 512KB (dead once attn done)
  bf16*     y2     = (bf16*)(w + 80 * MB);    // 8MB
  bf16*     psum0  = (bf16*)(w + 56 * MB);    // 8MB (ctx region, dead after O)
  bf16*     psum1  = (bf16*)(w + 80 * MB);    // 8MB (y2 region, dead after GELU)
  (void)in_sizes; (void)n_in; (void)out_size; (void)ws_size;

  prep_kernel<<<13312, 1024, 0, stream>>>(Wq, Wk, Wv, Wo, W1, W2, mask,
                                          Wqkv_t, Wo_t, W1_t, W2_t, mbits);

  layernorm_kernel<<<4096, 256, 0, stream>>>(x, ln1_g, ln1_b, y);

  gemm256_kernel<MODE_QKV, 128><<<dim3(24, 16), 512, 0, stream>>>(
      y, Wqkv_t, 4096, 3072, 1024, bq, bk, bv, nullptr,
      qb, kb, vt, nullptr);

  attn_kernel<<<256, 1024, 0, stream>>>(qb, kb, vt, mbits, ctx);

  gemm256_kernel<MODE_O, 64><<<dim3(16, 16), 512, 0, stream>>>(
      ctx, Wo_t, 4096, 1024, 1024, bo, nullptr, nullptr, x,
      nullptr, nullptr, nullptr, x2);

  layernorm_kernel<<<4096, 256, 0, stream>>>(x2, ln2_g, ln2_b, y2);

  gemm256sq_gelu_kernel<<<dim3(16, 16), 1024, 0, stream>>>(
      y2, W1_t, 4096, 4096, 1024, b1, hbuf);

  gemm_out_split_kernel<<<dim3(16, 32), 512, 0, stream>>>(
      hbuf, W2_t, 4096, psum0, psum1);

  reduce_out_kernel<<<4096, 256, 0, stream>>>(x2, b2, psum0, psum1, out);
}